// Round 9
// baseline (244.563 us; speedup 1.0000x reference)
//
#include <hip/hip_runtime.h>
#include <math.h>

// Problem constants (B=8,S=4096,D=1024,E=64,G=4,K=2, temperature=1)
#define TOKENS   32768
#define DDIM     1024
#define TPB      32                   // tokens per block
#define NBLOCKS  (TOKENS / TPB)       // 1024 blocks x 256 threads (4 waves = mt x khalf)

// Output layout (flat float32, tuple concat: idx, scores, probs, importance, load)
#define OFF_SCORES 65536
#define OFF_PROBS  131072
#define OFF_IMP    2228224
#define OFF_LOAD   2228288

#define NSLOT 16              // atomic spreading for importance/load partials

typedef __attribute__((ext_vector_type(8))) short  short8;  // 8 bf16 = 4 VGPR (MFMA A/B frag)
typedef __attribute__((ext_vector_type(4))) float  f32x4;   // MFMA C/D frag
typedef __attribute__((ext_vector_type(4))) int    intx4;

// Pre-split W fragments: [ks(32)][nt(5)][lvl(3)][lane(64)] x 16B. 480 KB, L2-resident.
// Rows 0..63 = experts, 64..67 = groups, 68..79 = zero pad.
__device__ __attribute__((aligned(16))) short wfrag[32 * 5 * 3 * 64 * 8];

// bf16 round-to-nearest-even of x, returned as the fp32 bit pattern.
__device__ inline unsigned rne_hi(float x) {
  unsigned u = __float_as_uint(x);
  unsigned r = u + 0x7fffu + ((u >> 16) & 1u);
  return r & 0xffff0000u;
}

// Split x (fp32) into 3 RNE-bf16 terms: x = a1 + a2 + a3 + O(2^-27 |x|).
__device__ inline void split3(const float* xv, short8& f1, short8& f2, short8& f3) {
  int o1[4], o2[4], o3[4];
  #pragma unroll
  for (int p = 0; p < 4; ++p) {
    float x0 = xv[2*p], x1 = xv[2*p+1];
    unsigned h0 = rne_hi(x0), h1 = rne_hi(x1);
    o1[p] = (int)((h0 >> 16) | (h1 & 0xffff0000u));
    float r0 = x0 - __uint_as_float(h0);
    float r1 = x1 - __uint_as_float(h1);
    unsigned g0 = rne_hi(r0), g1 = rne_hi(r1);
    o2[p] = (int)((g0 >> 16) | (g1 & 0xffff0000u));
    float s0 = r0 - __uint_as_float(g0);
    float s1 = r1 - __uint_as_float(g1);
    unsigned w0 = rne_hi(s0), w1 = rne_hi(s1);
    o3[p] = (int)((w0 >> 16) | (w1 & 0xffff0000u));
  }
  intx4 t1 = {o1[0], o1[1], o1[2], o1[3]};
  intx4 t2 = {o2[0], o2[1], o2[2], o2[3]};
  intx4 t3 = {o3[0], o3[1], o3[2], o3[3]};
  f1 = __builtin_bit_cast(short8, t1);
  f2 = __builtin_bit_cast(short8, t2);
  f3 = __builtin_bit_cast(short8, t3);
}

// Build W fragment splits. 160 blocks (nt*32+ks) x 64 threads.
__global__ void prep_kernel(const float* __restrict__ Wg, const float* __restrict__ We) {
  const int nt   = blockIdx.x >> 5;   // 0..4
  const int ks   = blockIdx.x & 31;   // 0..31
  const int lane = threadIdx.x & 63;
  const int row  = nt * 16 + (lane & 15);
  const int k0   = ks * 32 + (lane >> 4) * 8;
  float xv[8];
  #pragma unroll
  for (int j = 0; j < 8; ++j) {
    float v = 0.f;
    if (row < 64)      v = We[(size_t)row * DDIM + k0 + j];
    else if (row < 68) v = Wg[(size_t)(row - 64) * DDIM + k0 + j];
    xv[j] = v;
  }
  short8 f1, f2, f3;
  split3(xv, f1, f2, f3);
  short8* dst = (short8*)wfrag + (((size_t)ks * 5 + nt) * 3) * 64 + lane;
  dst[0]   = f1;
  dst[64]  = f2;
  dst[128] = f3;
}

// v3's exact per-token arithmetic graph. Wave = (mt, khalf): 40-VGPR acc,
// depth-1 B pipeline -> ~130 VGPR, 16 waves/CU for latency hiding.
__global__ __launch_bounds__(256, 3)
void router_kernel(const float* __restrict__ x,
                   float* __restrict__ out,
                   float* __restrict__ ws) {
  __shared__ __attribute__((aligned(16))) float el[TPB * 88];  // logits, stride 88
  __shared__ int cnt[64];
  const int tid    = threadIdx.x;
  const int lane   = tid & 63;
  const int wv     = tid >> 6;
  const int mt     = wv & 1;       // which 16-token m-tile
  const int khalf  = wv >> 1;      // which 512-wide K half (sequential 16 k-steps)
  const int quad   = lane >> 4;
  const int m      = lane & 15;
  const int tokblk = blockIdx.x * TPB;

  if (tid < 64) cnt[tid] = 0;

  // MFMA A-operand gather: lane holds A[row=m][k=quad*8+j]; one 16-token m-tile.
  const float* ap = x + (size_t)(tokblk + mt * 16 + m) * DDIM + khalf * 512 + quad * 8;

  // v3-verified numerics: a1b1 chain isolated in ahi; all cross terms in alo.
  f32x4 ahi[5], alo[5];
  #pragma unroll
  for (int nt = 0; nt < 5; ++nt) { ahi[nt] = 0.f; alo[nt] = 0.f; }

  const short8* bbase = (const short8*)wfrag + ((size_t)(khalf * 16) * 15) * 64 + lane;
  // current A and nt=0 B frags
  float4 a0 = *(const float4*)(ap), a1 = *(const float4*)(ap + 4);
  short8 b0 = bbase[0], b1 = bbase[64], b2 = bbase[128];

  for (int ks = 0; ks < 16; ++ks) {
    const short8* bp = bbase + (size_t)ks * 15 * 64;
    // prefetch next-ks A (long-latency path)
    float4 n0, n1;
    if (ks < 15) {
      const float* p = ap + (ks + 1) * 32;
      n0 = *(const float4*)(p);  n1 = *(const float4*)(p + 4);
    }
    short8 fa[3];
    {
      float av[8] = {a0.x, a0.y, a0.z, a0.w, a1.x, a1.y, a1.z, a1.w};
      split3(av, fa[0], fa[1], fa[2]);
    }
    // 8-pass split MFMA per nt; depth-1 B pipeline (load nt+1 before nt's MFMAs).
    // Per-accumulator chain order identical to v3/v7/v8 (bit-exact).
    #pragma unroll
    for (int nt = 0; nt < 5; ++nt) {
      short8 c0, c1, c2;
      if (nt < 4) {
        c0 = bp[(nt + 1) * 192];
        c1 = bp[(nt + 1) * 192 + 64];
        c2 = bp[(nt + 1) * 192 + 128];
      } else if (ks < 15) {                 // preload nt=0 of next ks
        c0 = bp[15 * 64];  c1 = bp[15 * 64 + 64];  c2 = bp[15 * 64 + 128];
      }
      ahi[nt] = __builtin_amdgcn_mfma_f32_16x16x32_bf16(fa[0], b0, ahi[nt], 0, 0, 0);
      f32x4 c = alo[nt];
      c = __builtin_amdgcn_mfma_f32_16x16x32_bf16(fa[0], b1, c, 0, 0, 0);
      c = __builtin_amdgcn_mfma_f32_16x16x32_bf16(fa[1], b0, c, 0, 0, 0);
      c = __builtin_amdgcn_mfma_f32_16x16x32_bf16(fa[1], b1, c, 0, 0, 0);
      c = __builtin_amdgcn_mfma_f32_16x16x32_bf16(fa[0], b2, c, 0, 0, 0);
      c = __builtin_amdgcn_mfma_f32_16x16x32_bf16(fa[2], b0, c, 0, 0, 0);
      c = __builtin_amdgcn_mfma_f32_16x16x32_bf16(fa[1], b2, c, 0, 0, 0);
      c = __builtin_amdgcn_mfma_f32_16x16x32_bf16(fa[2], b1, c, 0, 0, 0);
      alo[nt] = c;
      b0 = c0; b1 = c1; b2 = c2;
    }
    a0 = n0; a1 = n1;
  }

  // ---- K-half combine, v3's exact order: el = S1; el += S0 ----
  // C/D layout: col(n)=lane&15, row(m)=quad*4+reg
  if (khalf == 1) {
    #pragma unroll
    for (int nt = 0; nt < 5; ++nt)
      #pragma unroll
      for (int r = 0; r < 4; ++r)
        el[(mt * 16 + quad * 4 + r) * 88 + nt * 16 + m] = ahi[nt][r] + alo[nt][r];
  }
  __syncthreads();
  if (khalf == 0) {
    #pragma unroll
    for (int nt = 0; nt < 5; ++nt)
      #pragma unroll
      for (int r = 0; r < 4; ++r) {
        const int idx = (mt * 16 + quad * 4 + r) * 88 + nt * 16 + m;
        el[idx] += ahi[nt][r] + alo[nt][r];
      }
  }
  __syncthreads();

  // ---- epilogue: one token per thread (tid<32) ----
  if (tid < TPB) {
    const int t = tid;
    float* row = el + t * 88;
    const float g0 = row[64], g1 = row[65], g2 = row[66], g3 = row[67];
    int g = 0; float gb = g0;
    if (g1 > gb) { g = 1; gb = g1; }
    if (g2 > gb) { g = 2; gb = g2; }
    if (g3 > gb) { g = 3; gb = g3; }
    const int base = g << 4;
    float l[16];
    #pragma unroll
    for (int e = 0; e < 16; ++e) l[e] = row[base + e];
    int i1 = 0; float v1 = l[0];
    #pragma unroll
    for (int e = 1; e < 16; ++e) if (l[e] > v1) { i1 = e; v1 = l[e]; }
    int i2 = -1; float v2 = 0.f;
    #pragma unroll
    for (int e = 0; e < 16; ++e) {
      if (e == i1) continue;
      if (i2 < 0 || l[e] > v2) { i2 = e; v2 = l[e]; }
    }
    float pr[16]; float s = 0.f;
    #pragma unroll
    for (int e = 0; e < 16; ++e) { pr[e] = expf(l[e] - v1); s += pr[e]; }
    const float inv = 1.f / s;
    #pragma unroll
    for (int c = 0; c < 64; ++c) row[c] = 0.f;
    #pragma unroll
    for (int e = 0; e < 16; ++e) row[base + e] = pr[e] * inv;
    const size_t T = (size_t)tokblk + t;
    out[2*T]     = (float)(base + i1);
    out[2*T + 1] = (float)(base + i2);
    const float e2 = expf(v2 - v1);
    const float si = 1.f / (1.f + e2);
    out[OFF_SCORES + 2*T]     = si;
    out[OFF_SCORES + 2*T + 1] = e2 * si;
    atomicAdd(&cnt[base + i1], 1);
    atomicAdd(&cnt[base + i2], 1);
  }
  __syncthreads();

  // coalesced probs_full write
  for (int i = tid; i < TPB * 64; i += 256) {
    const int t = i >> 6, c = i & 63;
    out[OFF_PROBS + (((size_t)(tokblk + t)) << 6) + c] = el[t * 88 + c];
  }
  // block-partial importance & counts -> slot-spread global atomics
  if (tid < 64) {
    const int e = tid;
    float s = 0.f;
    #pragma unroll 4
    for (int t = 0; t < TPB; ++t) s += el[t * 88 + e];
    const int slot = (blockIdx.x & (NSLOT - 1)) * 128;
    atomicAdd(&ws[slot + e], s);
    atomicAdd(&ws[slot + 64 + e], (float)cnt[e]);
  }
}

__global__ void finalize_kernel(const float* __restrict__ ws, float* __restrict__ out) {
  const int e = threadIdx.x;
  if (e < 64) {
    float imp = 0.f, cf = 0.f;
    #pragma unroll
    for (int s = 0; s < NSLOT; ++s) {
      imp += ws[s * 128 + e];
      cf  += ws[s * 128 + 64 + e];
    }
    out[OFF_IMP  + e] = imp * (1.0f / 32768.0f);
    out[OFF_LOAD + e] = cf  * (1.0f / 65536.0f);   // counts sum == B*S*K
  }
}

extern "C" void kernel_launch(void* const* d_in, const int* in_sizes, int n_in,
                              void* d_out, int out_size, void* d_ws, size_t ws_size,
                              hipStream_t stream) {
  (void)in_sizes; (void)n_in; (void)out_size; (void)ws_size;
  const float* x  = (const float*)d_in[0];   // [8,4096,1024]
  const float* Wg = (const float*)d_in[1];   // [4,1024]
  const float* We = (const float*)d_in[2];   // [64,1024]
  float* out = (float*)d_out;
  float* ws  = (float*)d_ws;                 // NSLOT x (64 importance + 64 counts)
  hipMemsetAsync(d_ws, 0, NSLOT * 128 * sizeof(float), stream);
  hipLaunchKernelGGL(prep_kernel, dim3(160), dim3(64), 0, stream, Wg, We);
  hipLaunchKernelGGL(router_kernel, dim3(NBLOCKS), dim3(256), 0, stream, x, out, ws);
  hipLaunchKernelGGL(finalize_kernel, dim3(1), dim3(64), 0, stream, ws, out);
}

// Round 10
// 219.860 us; speedup vs baseline: 1.1124x; 1.1124x over previous
//
#include <hip/hip_runtime.h>
#include <math.h>

// Problem constants (B=8,S=4096,D=1024,E=64,G=4,K=2, temperature=1)
#define TOKENS   32768
#define DDIM     1024
#define TPB      32                   // tokens per block (2 m-tiles per wave)
#define NBLOCKS  (TOKENS / TPB)       // 1024 blocks x 128 threads (2 waves = K-halves)

// Output layout (flat float32, tuple concat: idx, scores, probs, importance, load)
#define OFF_SCORES 65536
#define OFF_PROBS  131072
#define OFF_IMP    2228224
#define OFF_LOAD   2228288

#define NSLOT 16              // atomic spreading for importance/load partials

typedef __attribute__((ext_vector_type(8))) short  short8;  // 8 bf16 = 4 VGPR (MFMA A/B frag)
typedef __attribute__((ext_vector_type(4))) float  f32x4;   // MFMA C/D frag
typedef __attribute__((ext_vector_type(4))) int    intx4;

// Pre-split W fragments: [ks(32)][nt(5)][lvl(3)][lane(64)] x 16B. 480 KB, L2-resident.
// Rows 0..63 = experts, 64..67 = groups, 68..79 = zero pad.
__device__ __attribute__((aligned(16))) short wfrag[32 * 5 * 3 * 64 * 8];

// bf16 round-to-nearest-even of x, returned as the fp32 bit pattern.
__device__ inline unsigned rne_hi(float x) {
  unsigned u = __float_as_uint(x);
  unsigned r = u + 0x7fffu + ((u >> 16) & 1u);
  return r & 0xffff0000u;
}

// Split x (fp32) into 3 RNE-bf16 terms: x = a1 + a2 + a3 + O(2^-27 |x|).
__device__ inline void split3(const float* xv, short8& f1, short8& f2, short8& f3) {
  int o1[4], o2[4], o3[4];
  #pragma unroll
  for (int p = 0; p < 4; ++p) {
    float x0 = xv[2*p], x1 = xv[2*p+1];
    unsigned h0 = rne_hi(x0), h1 = rne_hi(x1);
    o1[p] = (int)((h0 >> 16) | (h1 & 0xffff0000u));
    float r0 = x0 - __uint_as_float(h0);
    float r1 = x1 - __uint_as_float(h1);
    unsigned g0 = rne_hi(r0), g1 = rne_hi(r1);
    o2[p] = (int)((g0 >> 16) | (g1 & 0xffff0000u));
    float s0 = r0 - __uint_as_float(g0);
    float s1 = r1 - __uint_as_float(g1);
    unsigned w0 = rne_hi(s0), w1 = rne_hi(s1);
    o3[p] = (int)((w0 >> 16) | (w1 & 0xffff0000u));
  }
  intx4 t1 = {o1[0], o1[1], o1[2], o1[3]};
  intx4 t2 = {o2[0], o2[1], o2[2], o2[3]};
  intx4 t3 = {o3[0], o3[1], o3[2], o3[3]};
  f1 = __builtin_bit_cast(short8, t1);
  f2 = __builtin_bit_cast(short8, t2);
  f3 = __builtin_bit_cast(short8, t3);
}

// Build W fragment splits. 160 blocks (nt*32+ks) x 64 threads.
__global__ void prep_kernel(const float* __restrict__ Wg, const float* __restrict__ We) {
  const int nt   = blockIdx.x >> 5;   // 0..4
  const int ks   = blockIdx.x & 31;   // 0..31
  const int lane = threadIdx.x & 63;
  const int row  = nt * 16 + (lane & 15);
  const int k0   = ks * 32 + (lane >> 4) * 8;
  float xv[8];
  #pragma unroll
  for (int j = 0; j < 8; ++j) {
    float v = 0.f;
    if (row < 64)      v = We[(size_t)row * DDIM + k0 + j];
    else if (row < 68) v = Wg[(size_t)(row - 64) * DDIM + k0 + j];
    xv[j] = v;
  }
  short8 f1, f2, f3;
  split3(xv, f1, f2, f3);
  short8* dst = (short8*)wfrag + (((size_t)ks * 5 + nt) * 3) * 64 + lane;
  dst[0]   = f1;
  dst[64]  = f2;
  dst[128] = f3;
}

// v3's exact per-token arithmetic graph; 1024x128 grid, 2 m-tiles/wave.
// amdgpu_waves_per_eu(2,2) pins the scheduler at 2 waves/EU (256-VGPR budget)
// so fb(60)+acc(80)+depth-2 A queue(48) stay register-resident — v7/v9 showed
// the occupancy heuristic otherwise squeezes to 64 VGPR and serializes loads.
__global__ __launch_bounds__(128)
__attribute__((amdgpu_waves_per_eu(2, 2)))
void router_kernel(const float* __restrict__ x,
                   float* __restrict__ out,
                   float* __restrict__ ws) {
  __shared__ __attribute__((aligned(16))) float el[TPB * 88];  // logits, stride 88
  __shared__ int cnt[64];
  const int tid    = threadIdx.x;
  const int lane   = tid & 63;
  const int khalf  = tid >> 6;     // wave id = K-half (512-wide, sequential 16 k-steps)
  const int quad   = lane >> 4;
  const int m      = lane & 15;
  const int tokblk = blockIdx.x * TPB;

  if (tid < 64) cnt[tid] = 0;

  // MFMA A-operand gather: lane holds A[row=m][k=quad*8+j]; two 16-token m-tiles.
  const float* ap0 = x + (size_t)(tokblk + m) * DDIM + khalf * 512 + quad * 8;
  const float* ap1 = ap0 + (size_t)16 * DDIM;

  // v3-verified numerics: a1b1 chain isolated in ahi; all cross terms in alo.
  f32x4 ahi[2][5], alo[2][5];
  #pragma unroll
  for (int mt = 0; mt < 2; ++mt)
    #pragma unroll
    for (int nt = 0; nt < 5; ++nt) { ahi[mt][nt] = 0.f; alo[mt][nt] = 0.f; }

  // depth-2 A prefetch pipeline: c = ks, p = ks+1 (HBM latency ~900cyc < 2 k-steps)
  float4 c0 = *(const float4*)(ap0),      c1 = *(const float4*)(ap0 + 4);
  float4 c2 = *(const float4*)(ap1),      c3 = *(const float4*)(ap1 + 4);
  float4 p0 = *(const float4*)(ap0 + 32), p1 = *(const float4*)(ap0 + 36);
  float4 p2 = *(const float4*)(ap1 + 32), p3 = *(const float4*)(ap1 + 36);

  for (int ks = 0; ks < 16; ++ks) {
    // B fragments for this K-step — issued first so latency overlaps split3 VALU
    const short8* bp = (const short8*)wfrag + ((size_t)(khalf * 16 + ks) * 15) * 64 + lane;
    short8 fb[5][3];
    #pragma unroll
    for (int nt = 0; nt < 5; ++nt) {
      fb[nt][0] = bp[nt * 192];
      fb[nt][1] = bp[nt * 192 + 64];
      fb[nt][2] = bp[nt * 192 + 128];
    }
    // prefetch A for ks+2 (clamped; last 2 iters re-load ks=15, discarded)
    const int kpf = (ks + 2 < 16) ? (ks + 2) : 15;
    float4 q0, q1, q2, q3;
    {
      const float* f0 = ap0 + kpf * 32;
      const float* f1p = ap1 + kpf * 32;
      q0 = *(const float4*)(f0);   q1 = *(const float4*)(f0 + 4);
      q2 = *(const float4*)(f1p);  q3 = *(const float4*)(f1p + 4);
    }
    short8 fa[2][3];
    {
      float av[8] = {c0.x, c0.y, c0.z, c0.w, c1.x, c1.y, c1.z, c1.w};
      split3(av, fa[0][0], fa[0][1], fa[0][2]);
      float bv[8] = {c2.x, c2.y, c2.z, c2.w, c3.x, c3.y, c3.z, c3.w};
      split3(bv, fa[1][0], fa[1][1], fa[1][2]);
    }
    // 8-pass split MFMA: a1b1 -> hi; all cross terms -> lo (only a3b3 dropped)
    // per-accumulator chain order preserved exactly (bit-exact vs v3/v8)
    #pragma unroll
    for (int nt = 0; nt < 5; ++nt)
      #pragma unroll
      for (int mt = 0; mt < 2; ++mt) {
        ahi[mt][nt] = __builtin_amdgcn_mfma_f32_16x16x32_bf16(fa[mt][0], fb[nt][0], ahi[mt][nt], 0, 0, 0);
        f32x4 c = alo[mt][nt];
        c = __builtin_amdgcn_mfma_f32_16x16x32_bf16(fa[mt][0], fb[nt][1], c, 0, 0, 0);
        c = __builtin_amdgcn_mfma_f32_16x16x32_bf16(fa[mt][1], fb[nt][0], c, 0, 0, 0);
        c = __builtin_amdgcn_mfma_f32_16x16x32_bf16(fa[mt][1], fb[nt][1], c, 0, 0, 0);
        c = __builtin_amdgcn_mfma_f32_16x16x32_bf16(fa[mt][0], fb[nt][2], c, 0, 0, 0);
        c = __builtin_amdgcn_mfma_f32_16x16x32_bf16(fa[mt][2], fb[nt][0], c, 0, 0, 0);
        c = __builtin_amdgcn_mfma_f32_16x16x32_bf16(fa[mt][1], fb[nt][2], c, 0, 0, 0);
        c = __builtin_amdgcn_mfma_f32_16x16x32_bf16(fa[mt][2], fb[nt][1], c, 0, 0, 0);
        alo[mt][nt] = c;
      }
    c0 = p0; c1 = p1; c2 = p2; c3 = p3;
    p0 = q0; p1 = q1; p2 = q2; p3 = q3;
  }

  // ---- K-half combine, v3's exact order: el = S1; el += S0 ----
  // C/D layout: col(n)=lane&15, row(m)=quad*4+reg
  if (khalf == 1) {
    #pragma unroll
    for (int mt = 0; mt < 2; ++mt)
      #pragma unroll
      for (int nt = 0; nt < 5; ++nt)
        #pragma unroll
        for (int r = 0; r < 4; ++r)
          el[(mt * 16 + quad * 4 + r) * 88 + nt * 16 + m] = ahi[mt][nt][r] + alo[mt][nt][r];
  }
  __syncthreads();
  if (khalf == 0) {
    #pragma unroll
    for (int mt = 0; mt < 2; ++mt)
      #pragma unroll
      for (int nt = 0; nt < 5; ++nt)
        #pragma unroll
        for (int r = 0; r < 4; ++r) {
          const int idx = (mt * 16 + quad * 4 + r) * 88 + nt * 16 + m;
          el[idx] += ahi[mt][nt][r] + alo[mt][nt][r];
        }
  }
  __syncthreads();

  // ---- epilogue: one token per thread (tid<32) ----
  if (tid < TPB) {
    const int t = tid;
    float* row = el + t * 88;
    const float g0 = row[64], g1 = row[65], g2 = row[66], g3 = row[67];
    int g = 0; float gb = g0;
    if (g1 > gb) { g = 1; gb = g1; }
    if (g2 > gb) { g = 2; gb = g2; }
    if (g3 > gb) { g = 3; gb = g3; }
    const int base = g << 4;
    float l[16];
    #pragma unroll
    for (int e = 0; e < 16; ++e) l[e] = row[base + e];
    int i1 = 0; float v1 = l[0];
    #pragma unroll
    for (int e = 1; e < 16; ++e) if (l[e] > v1) { i1 = e; v1 = l[e]; }
    int i2 = -1; float v2 = 0.f;
    #pragma unroll
    for (int e = 0; e < 16; ++e) {
      if (e == i1) continue;
      if (i2 < 0 || l[e] > v2) { i2 = e; v2 = l[e]; }
    }
    float pr[16]; float s = 0.f;
    #pragma unroll
    for (int e = 0; e < 16; ++e) { pr[e] = expf(l[e] - v1); s += pr[e]; }
    const float inv = 1.f / s;
    #pragma unroll
    for (int c = 0; c < 64; ++c) row[c] = 0.f;
    #pragma unroll
    for (int e = 0; e < 16; ++e) row[base + e] = pr[e] * inv;
    const size_t T = (size_t)tokblk + t;
    out[2*T]     = (float)(base + i1);
    out[2*T + 1] = (float)(base + i2);
    const float e2 = expf(v2 - v1);
    const float si = 1.f / (1.f + e2);
    out[OFF_SCORES + 2*T]     = si;
    out[OFF_SCORES + 2*T + 1] = e2 * si;
    atomicAdd(&cnt[base + i1], 1);
    atomicAdd(&cnt[base + i2], 1);
  }
  __syncthreads();

  // coalesced probs_full write
  for (int i = tid; i < TPB * 64; i += 128) {
    const int t = i >> 6, c = i & 63;
    out[OFF_PROBS + (((size_t)(tokblk + t)) << 6) + c] = el[t * 88 + c];
  }
  // block-partial importance & counts -> slot-spread global atomics
  if (tid < 64) {
    const int e = tid;
    float s = 0.f;
    #pragma unroll 4
    for (int t = 0; t < TPB; ++t) s += el[t * 88 + e];
    const int slot = (blockIdx.x & (NSLOT - 1)) * 128;
    atomicAdd(&ws[slot + e], s);
    atomicAdd(&ws[slot + 64 + e], (float)cnt[e]);
  }
}

__global__ void finalize_kernel(const float* __restrict__ ws, float* __restrict__ out) {
  const int e = threadIdx.x;
  if (e < 64) {
    float imp = 0.f, cf = 0.f;
    #pragma unroll
    for (int s = 0; s < NSLOT; ++s) {
      imp += ws[s * 128 + e];
      cf  += ws[s * 128 + 64 + e];
    }
    out[OFF_IMP  + e] = imp * (1.0f / 32768.0f);
    out[OFF_LOAD + e] = cf  * (1.0f / 65536.0f);   // counts sum == B*S*K
  }
}

extern "C" void kernel_launch(void* const* d_in, const int* in_sizes, int n_in,
                              void* d_out, int out_size, void* d_ws, size_t ws_size,
                              hipStream_t stream) {
  (void)in_sizes; (void)n_in; (void)out_size; (void)ws_size;
  const float* x  = (const float*)d_in[0];   // [8,4096,1024]
  const float* Wg = (const float*)d_in[1];   // [4,1024]
  const float* We = (const float*)d_in[2];   // [64,1024]
  float* out = (float*)d_out;
  float* ws  = (float*)d_ws;                 // NSLOT x (64 importance + 64 counts)
  hipMemsetAsync(d_ws, 0, NSLOT * 128 * sizeof(float), stream);
  hipLaunchKernelGGL(prep_kernel, dim3(160), dim3(64), 0, stream, Wg, We);
  hipLaunchKernelGGL(router_kernel, dim3(NBLOCKS), dim3(128), 0, stream, x, out, ws);
  hipLaunchKernelGGL(finalize_kernel, dim3(1), dim3(64), 0, stream, ws, out);
}

// Round 11
// 209.799 us; speedup vs baseline: 1.1657x; 1.0480x over previous
//
#include <hip/hip_runtime.h>
#include <math.h>

// Problem constants (B=8,S=4096,D=1024,E=64,G=4,K=2, temperature=1)
#define TOKENS   32768
#define DDIM     1024
#define TPB      64                   // tokens per block (4 m-tiles per wave)
#define NBLOCKS  (TOKENS / TPB)       // 512 blocks x 128 threads (2 waves = K-halves)

// Output layout (flat float32, tuple concat: idx, scores, probs, importance, load)
#define OFF_SCORES 65536
#define OFF_PROBS  131072
#define OFF_IMP    2228224
#define OFF_LOAD   2228288

#define NSLOT 16              // atomic spreading for importance/load partials

typedef __attribute__((ext_vector_type(8))) short  short8;  // 8 bf16 = 4 VGPR (MFMA A/B frag)
typedef __attribute__((ext_vector_type(4))) float  f32x4;   // MFMA C/D frag
typedef __attribute__((ext_vector_type(4))) int    intx4;

// Pre-split W fragments: [ks(32)][nt(5)][lvl(3)][lane(64)] x 16B. 480 KB, L2-resident.
// Rows 0..63 = experts, 64..67 = groups, 68..79 = zero pad.
__device__ __attribute__((aligned(16))) short wfrag[32 * 5 * 3 * 64 * 8];

// bf16 round-to-nearest-even of x, returned as the fp32 bit pattern.
__device__ inline unsigned rne_hi(float x) {
  unsigned u = __float_as_uint(x);
  unsigned r = u + 0x7fffu + ((u >> 16) & 1u);
  return r & 0xffff0000u;
}

// Split x (fp32) into 3 RNE-bf16 terms: x = a1 + a2 + a3 + O(2^-27 |x|).
__device__ inline void split3(const float* xv, short8& f1, short8& f2, short8& f3) {
  int o1[4], o2[4], o3[4];
  #pragma unroll
  for (int p = 0; p < 4; ++p) {
    float x0 = xv[2*p], x1 = xv[2*p+1];
    unsigned h0 = rne_hi(x0), h1 = rne_hi(x1);
    o1[p] = (int)((h0 >> 16) | (h1 & 0xffff0000u));
    float r0 = x0 - __uint_as_float(h0);
    float r1 = x1 - __uint_as_float(h1);
    unsigned g0 = rne_hi(r0), g1 = rne_hi(r1);
    o2[p] = (int)((g0 >> 16) | (g1 & 0xffff0000u));
    float s0 = r0 - __uint_as_float(g0);
    float s1 = r1 - __uint_as_float(g1);
    unsigned w0 = rne_hi(s0), w1 = rne_hi(s1);
    o3[p] = (int)((w0 >> 16) | (w1 & 0xffff0000u));
  }
  intx4 t1 = {o1[0], o1[1], o1[2], o1[3]};
  intx4 t2 = {o2[0], o2[1], o2[2], o2[3]};
  intx4 t3 = {o3[0], o3[1], o3[2], o3[3]};
  f1 = __builtin_bit_cast(short8, t1);
  f2 = __builtin_bit_cast(short8, t2);
  f3 = __builtin_bit_cast(short8, t3);
}

// Build W fragment splits. 160 blocks (nt*32+ks) x 64 threads.
__global__ void prep_kernel(const float* __restrict__ Wg, const float* __restrict__ We) {
  const int nt   = blockIdx.x >> 5;   // 0..4
  const int ks   = blockIdx.x & 31;   // 0..31
  const int lane = threadIdx.x & 63;
  const int row  = nt * 16 + (lane & 15);
  const int k0   = ks * 32 + (lane >> 4) * 8;
  float xv[8];
  #pragma unroll
  for (int j = 0; j < 8; ++j) {
    float v = 0.f;
    if (row < 64)      v = We[(size_t)row * DDIM + k0 + j];
    else if (row < 68) v = Wg[(size_t)(row - 64) * DDIM + k0 + j];
    xv[j] = v;
  }
  short8 f1, f2, f3;
  split3(xv, f1, f2, f3);
  short8* dst = (short8*)wfrag + (((size_t)ks * 5 + nt) * 3) * 64 + lane;
  dst[0]   = f1;
  dst[64]  = f2;
  dst[128] = f3;
}

// v3's exact per-token arithmetic graph; 4 m-tiles per wave to cut the
// vmem:MFMA ratio (23 loads per 160 MFMAs vs 19 per 80). waves_per_eu(1,1)
// gives 1 wave/SIMD with the full unified VGPR/AGPR budget (~512, m08) so
// acc(160)+fb(60)+A(64)+fa(48) all stay register-resident.
__global__ __launch_bounds__(128)
__attribute__((amdgpu_waves_per_eu(1, 1)))
void router_kernel(const float* __restrict__ x,
                   float* __restrict__ out,
                   float* __restrict__ ws) {
  __shared__ __attribute__((aligned(16))) float el[TPB * 88];  // logits, stride 88
  __shared__ int cnt[64];
  const int tid    = threadIdx.x;
  const int lane   = tid & 63;
  const int khalf  = tid >> 6;     // wave id = K-half (512-wide, sequential 16 k-steps)
  const int quad   = lane >> 4;
  const int m      = lane & 15;
  const int tokblk = blockIdx.x * TPB;

  if (tid < 64) cnt[tid] = 0;

  // MFMA A-operand gather: lane holds A[row=m][k=quad*8+j]; four 16-token m-tiles.
  const float* apb = x + (size_t)(tokblk + m) * DDIM + khalf * 512 + quad * 8;

  // v3-verified numerics: a1b1 chain isolated in ahi; all cross terms in alo.
  f32x4 ahi[4][5], alo[4][5];
  #pragma unroll
  for (int mt = 0; mt < 4; ++mt)
    #pragma unroll
    for (int nt = 0; nt < 5; ++nt) { ahi[mt][nt] = 0.f; alo[mt][nt] = 0.f; }

  // depth-1 A prefetch: cur = ks, loaded into nxt during previous step
  float4 cur[8], nxt[8];
  #pragma unroll
  for (int mt = 0; mt < 4; ++mt) {
    const float* p = apb + (size_t)(mt * 16) * DDIM;
    cur[mt * 2]     = *(const float4*)(p);
    cur[mt * 2 + 1] = *(const float4*)(p + 4);
  }

  for (int ks = 0; ks < 16; ++ks) {
    // B fragments for this K-step — issued first; split3 VALU covers their latency
    const short8* bp = (const short8*)wfrag + ((size_t)(khalf * 16 + ks) * 15) * 64 + lane;
    short8 fb[5][3];
    #pragma unroll
    for (int nt = 0; nt < 5; ++nt) {
      fb[nt][0] = bp[nt * 192];
      fb[nt][1] = bp[nt * 192 + 64];
      fb[nt][2] = bp[nt * 192 + 128];
    }
    // prefetch A for ks+1 (clamped on last iter, discarded)
    const int kpf = (ks + 1 < 16) ? (ks + 1) : 15;
    #pragma unroll
    for (int mt = 0; mt < 4; ++mt) {
      const float* p = apb + (size_t)(mt * 16) * DDIM + kpf * 32;
      nxt[mt * 2]     = *(const float4*)(p);
      nxt[mt * 2 + 1] = *(const float4*)(p + 4);
    }
    // split current A -> 3 bf16 fragments per m-tile
    short8 fa[4][3];
    #pragma unroll
    for (int mt = 0; mt < 4; ++mt) {
      float av[8] = {cur[mt*2].x, cur[mt*2].y, cur[mt*2].z, cur[mt*2].w,
                     cur[mt*2+1].x, cur[mt*2+1].y, cur[mt*2+1].z, cur[mt*2+1].w};
      split3(av, fa[mt][0], fa[mt][1], fa[mt][2]);
    }
    // 8-pass split MFMA: a1b1 -> hi; all cross terms -> lo (only a3b3 dropped)
    // per-accumulator chain order preserved exactly (bit-exact vs v3/v8/v10)
    #pragma unroll
    for (int nt = 0; nt < 5; ++nt)
      #pragma unroll
      for (int mt = 0; mt < 4; ++mt) {
        ahi[mt][nt] = __builtin_amdgcn_mfma_f32_16x16x32_bf16(fa[mt][0], fb[nt][0], ahi[mt][nt], 0, 0, 0);
        f32x4 c = alo[mt][nt];
        c = __builtin_amdgcn_mfma_f32_16x16x32_bf16(fa[mt][0], fb[nt][1], c, 0, 0, 0);
        c = __builtin_amdgcn_mfma_f32_16x16x32_bf16(fa[mt][1], fb[nt][0], c, 0, 0, 0);
        c = __builtin_amdgcn_mfma_f32_16x16x32_bf16(fa[mt][1], fb[nt][1], c, 0, 0, 0);
        c = __builtin_amdgcn_mfma_f32_16x16x32_bf16(fa[mt][0], fb[nt][2], c, 0, 0, 0);
        c = __builtin_amdgcn_mfma_f32_16x16x32_bf16(fa[mt][2], fb[nt][0], c, 0, 0, 0);
        c = __builtin_amdgcn_mfma_f32_16x16x32_bf16(fa[mt][1], fb[nt][2], c, 0, 0, 0);
        c = __builtin_amdgcn_mfma_f32_16x16x32_bf16(fa[mt][2], fb[nt][1], c, 0, 0, 0);
        alo[mt][nt] = c;
      }
    #pragma unroll
    for (int i = 0; i < 8; ++i) cur[i] = nxt[i];
  }

  // ---- K-half combine, v3's exact order: el = S1; el += S0 ----
  // C/D layout: col(n)=lane&15, row(m)=quad*4+reg
  if (khalf == 1) {
    #pragma unroll
    for (int mt = 0; mt < 4; ++mt)
      #pragma unroll
      for (int nt = 0; nt < 5; ++nt)
        #pragma unroll
        for (int r = 0; r < 4; ++r)
          el[(mt * 16 + quad * 4 + r) * 88 + nt * 16 + m] = ahi[mt][nt][r] + alo[mt][nt][r];
  }
  __syncthreads();
  if (khalf == 0) {
    #pragma unroll
    for (int mt = 0; mt < 4; ++mt)
      #pragma unroll
      for (int nt = 0; nt < 5; ++nt)
        #pragma unroll
        for (int r = 0; r < 4; ++r) {
          const int idx = (mt * 16 + quad * 4 + r) * 88 + nt * 16 + m;
          el[idx] += ahi[mt][nt][r] + alo[mt][nt][r];
        }
  }
  __syncthreads();

  // ---- epilogue: one token per thread (tid<64) ----
  if (tid < TPB) {
    const int t = tid;
    float* row = el + t * 88;
    const float g0 = row[64], g1 = row[65], g2 = row[66], g3 = row[67];
    int g = 0; float gb = g0;
    if (g1 > gb) { g = 1; gb = g1; }
    if (g2 > gb) { g = 2; gb = g2; }
    if (g3 > gb) { g = 3; gb = g3; }
    const int base = g << 4;
    float l[16];
    #pragma unroll
    for (int e = 0; e < 16; ++e) l[e] = row[base + e];
    int i1 = 0; float v1 = l[0];
    #pragma unroll
    for (int e = 1; e < 16; ++e) if (l[e] > v1) { i1 = e; v1 = l[e]; }
    int i2 = -1; float v2 = 0.f;
    #pragma unroll
    for (int e = 0; e < 16; ++e) {
      if (e == i1) continue;
      if (i2 < 0 || l[e] > v2) { i2 = e; v2 = l[e]; }
    }
    float pr[16]; float s = 0.f;
    #pragma unroll
    for (int e = 0; e < 16; ++e) { pr[e] = expf(l[e] - v1); s += pr[e]; }
    const float inv = 1.f / s;
    #pragma unroll
    for (int c = 0; c < 64; ++c) row[c] = 0.f;
    #pragma unroll
    for (int e = 0; e < 16; ++e) row[base + e] = pr[e] * inv;
    const size_t T = (size_t)tokblk + t;
    out[2*T]     = (float)(base + i1);
    out[2*T + 1] = (float)(base + i2);
    const float e2 = expf(v2 - v1);
    const float si = 1.f / (1.f + e2);
    out[OFF_SCORES + 2*T]     = si;
    out[OFF_SCORES + 2*T + 1] = e2 * si;
    atomicAdd(&cnt[base + i1], 1);
    atomicAdd(&cnt[base + i2], 1);
  }
  __syncthreads();

  // coalesced probs_full write
  for (int i = tid; i < TPB * 64; i += 128) {
    const int t = i >> 6, c = i & 63;
    out[OFF_PROBS + (((size_t)(tokblk + t)) << 6) + c] = el[t * 88 + c];
  }
  // block-partial importance & counts -> slot-spread global atomics
  if (tid < 64) {
    const int e = tid;
    float s = 0.f;
    #pragma unroll 4
    for (int t = 0; t < TPB; ++t) s += el[t * 88 + e];
    const int slot = (blockIdx.x & (NSLOT - 1)) * 128;
    atomicAdd(&ws[slot + e], s);
    atomicAdd(&ws[slot + 64 + e], (float)cnt[e]);
  }
}

__global__ void finalize_kernel(const float* __restrict__ ws, float* __restrict__ out) {
  const int e = threadIdx.x;
  if (e < 64) {
    float imp = 0.f, cf = 0.f;
    #pragma unroll
    for (int s = 0; s < NSLOT; ++s) {
      imp += ws[s * 128 + e];
      cf  += ws[s * 128 + 64 + e];
    }
    out[OFF_IMP  + e] = imp * (1.0f / 32768.0f);
    out[OFF_LOAD + e] = cf  * (1.0f / 65536.0f);   // counts sum == B*S*K
  }
}

extern "C" void kernel_launch(void* const* d_in, const int* in_sizes, int n_in,
                              void* d_out, int out_size, void* d_ws, size_t ws_size,
                              hipStream_t stream) {
  (void)in_sizes; (void)n_in; (void)out_size; (void)ws_size;
  const float* x  = (const float*)d_in[0];   // [8,4096,1024]
  const float* Wg = (const float*)d_in[1];   // [4,1024]
  const float* We = (const float*)d_in[2];   // [64,1024]
  float* out = (float*)d_out;
  float* ws  = (float*)d_ws;                 // NSLOT x (64 importance + 64 counts)
  hipMemsetAsync(d_ws, 0, NSLOT * 128 * sizeof(float), stream);
  hipLaunchKernelGGL(prep_kernel, dim3(160), dim3(64), 0, stream, Wg, We);
  hipLaunchKernelGGL(router_kernel, dim3(NBLOCKS), dim3(128), 0, stream, x, out, ws);
  hipLaunchKernelGGL(finalize_kernel, dim3(1), dim3(64), 0, stream, ws, out);
}